// Round 7
// baseline (576.606 us; speedup 1.0000x reference)
//
#include <hip/hip_runtime.h>
#include <hip/hip_bf16.h>
#include <hip/hip_cooperative_groups.h>

namespace cg = cooperative_groups;

#define N_NODES 50000
#define N_EDGES 600000
#define D 128
#define K2 256     // 2*D
#define MAXDEG 64  // Poisson(12): max over 50K nodes ~ 33; 64 is safe capacity
#define LAYER_TILES ((N_NODES + 31) / 32)   // 1563
#define MAX_GRID 1024

typedef __bf16 bf16x8 __attribute__((ext_vector_type(8)));
typedef float  f32x16 __attribute__((ext_vector_type(16)));

__device__ __forceinline__ unsigned short f32_to_bf16_rne(float f) {
    unsigned int u = __builtin_bit_cast(unsigned int, f);
    unsigned int r = (u + 0x7fffu + ((u >> 16) & 1u)) >> 16;
    return (unsigned short)r;
}
__device__ __forceinline__ unsigned pk2(float lo, float hi) {
    return (unsigned)f32_to_bf16_rne(lo) | ((unsigned)f32_to_bf16_rne(hi) << 16);
}
__device__ __forceinline__ float bfl(unsigned int u) { return __builtin_bit_cast(float, u << 16); }
__device__ __forceinline__ float bfh(unsigned int u) { return __builtin_bit_cast(float, u & 0xffff0000u); }

// ---------- one layer tile: group-per-node gather (asm-forced MLP) -> LDS -> MFMA ----------
// 256 thr (4 waves), 32 nodes; wave handles 8 nodes as 2 slots x 4 groups.
// Lane = (g,u): g=lane>>4 node within slot, u=lane&15 uint4 of the 256B row.
// Gather per 16-edge chunk: A) 16 bpermutes -> clamped idx; B) 16 asm
// global_load_dwordx4 (order-pinned, 64 data VGPRs in flight) -> vmcnt(0) ->
// sched_barrier(0) [rule #18]; C) masked accumulate.
// LDS As4[frag*33+m]; GEMM: wave wv cols [wv*32,wv*32+32), K=256, 16x MFMA
// 32x32x16 bf16. C/D: col=lane&31, row=(reg&3)+8*(reg>>2)+4*(lane>>5).
template <bool RELU, bool OUT_BF16>
__device__ __forceinline__ void layer_tile(
    int base, uint4* As4,
    const unsigned short* __restrict__ Xin,   // [N][128] bf16
    const int* __restrict__ counts, const int* __restrict__ slots,
    const unsigned short* __restrict__ WT,    // [128][256] bf16 (one layer)
    const float* __restrict__ bias,
    unsigned short* __restrict__ Hout,        // RELU layer: bf16 [N][128]
    float* __restrict__ outf)                 // final layer: f32 [N][128]
{
    const int tid = threadIdx.x;
    const int lane = tid & 63;
    const int wv = tid >> 6;                  // wave 0..3
    const int g = lane >> 4;                  // node-group 0..3
    const int u = lane & 15;                  // uint4 within row
    const uint4* X4 = (const uint4*)Xin;      // row stride = 16 uint4
    const int nodeb = base + wv * 8;

    const int n0 = nodeb + g;                 // slot-0 node of this group
    const int n1 = nodeb + 4 + g;             // slot-1 node
    const bool ok0 = n0 < N_NODES, ok1 = n1 < N_NODES;

    // ---- issue independent loads up front ----
    int cnt0 = 0, cnt1 = 0;
    if (ok0) cnt0 = counts[n0];
    if (ok1) cnt1 = counts[n1];

    int sreg[2][4];                           // slot rows distributed over lanes
    #pragma unroll
    for (int r = 0; r < 4; ++r) {
        sreg[0][r] = ok0 ? slots[(size_t)n0 * MAXDEG + r * 16 + u] : 0;
        sreg[1][r] = ok1 ? slots[(size_t)n1 * MAXDEG + r * 16 + u] : 0;
    }

    uint4 xv0 = {0u,0u,0u,0u}, xv1 = {0u,0u,0u,0u};   // self rows (written at end)
    if (ok0) xv0 = X4[(size_t)n0 * 16 + u];
    if (ok1) xv1 = X4[(size_t)n1 * 16 + u];

    cnt0 = cnt0 > MAXDEG ? MAXDEG : cnt0;
    cnt1 = cnt1 > MAXDEG ? MAXDEG : cnt1;

    // ---- gather: 2 slots ----
    #pragma unroll
    for (int s = 0; s < 2; ++s) {
        const int m = wv * 8 + s * 4 + g;
        const int cnt = s ? cnt1 : cnt0;
        float a0 = 0.f, a1 = 0.f, a2 = 0.f, a3 = 0.f;
        float a4 = 0.f, a5 = 0.f, a6 = 0.f, a7 = 0.f;

        #pragma unroll
        for (int r = 0; r < 4; ++r) {
            if (r == 0 || __any(cnt > r * 16)) {
                // A: indices (clamped -> safe unconditional loads)
                int idxv[16];
                #pragma unroll
                for (int e = 0; e < 16; ++e) {
                    int t = __shfl(sreg[s][r], g * 16 + e, 64);
                    idxv[e] = (r * 16 + e < cnt) ? t : 0;
                }
                // B: 16 order-pinned loads in flight
                uint4 vv[16];
                #pragma unroll
                for (int e = 0; e < 16; ++e) {
                    const uint4* p = X4 + (size_t)idxv[e] * 16 + u;
                    asm volatile("global_load_dwordx4 %0, %1, off"
                                 : "=v"(vv[e]) : "v"(p) : "memory");
                }
                asm volatile("s_waitcnt vmcnt(0)" ::: "memory");
                __builtin_amdgcn_sched_barrier(0);
                // C: masked accumulate
                #pragma unroll
                for (int e = 0; e < 16; ++e) {
                    if (r * 16 + e < cnt) {
                        a0 += bfl(vv[e].x); a1 += bfh(vv[e].x);
                        a2 += bfl(vv[e].y); a3 += bfh(vv[e].y);
                        a4 += bfl(vv[e].z); a5 += bfh(vv[e].z);
                        a6 += bfl(vv[e].w); a7 += bfh(vv[e].w);
                    }
                }
            }
        }

        const float inv = 1.0f / fmaxf((float)cnt, 1.0f);
        uint4 o;
        o.x = pk2(a0 * inv, a1 * inv); o.y = pk2(a2 * inv, a3 * inv);
        o.z = pk2(a4 * inv, a5 * inv); o.w = pk2(a6 * inv, a7 * inv);
        As4[u * 33 + m] = o;                  // all 64 lanes: 4 nodes at once
    }

    // self half: frag 16+u
    As4[(16 + u) * 33 + (wv * 8 + g)]     = xv0;
    As4[(16 + u) * 33 + (wv * 8 + 4 + g)] = xv1;

    __syncthreads();

    // ---- GEMM phase ----
    const int m = lane & 31;
    const int kg = lane >> 5;
    const int col = wv * 32 + m;
    const uint4* bp = (const uint4*)(WT + (size_t)col * K2 + kg * 8);
    const bf16x8* afrag = (const bf16x8*)As4;

    f32x16 acc = {};
    #pragma unroll
    for (int s = 0; s < 16; ++s) {
        bf16x8 a = afrag[(s * 2 + kg) * 33 + m];
        bf16x8 b = __builtin_bit_cast(bf16x8, bp[s * 2]);
        acc = __builtin_amdgcn_mfma_f32_32x32x16_bf16(a, b, acc, 0, 0, 0);
    }

    const float bc = bias[col];
    const int halfadd = kg * 4;
    #pragma unroll
    for (int r = 0; r < 16; ++r) {
        int rw = base + (r & 3) + 8 * (r >> 2) + halfadd;
        if (rw < N_NODES) {
            float v = acc[r] + bc;
            if (RELU) v = fmaxf(v, 0.0f);
            if (OUT_BF16) Hout[(size_t)rw * D + col] = f32_to_bf16_rne(v);
            else outf[(size_t)rw * D + col] = v;
        }
    }
}

// dynamic tile-stealing driver for one layer phase
template <bool RELU, bool OUT_BF16>
__device__ __forceinline__ void layer_phase(
    uint4* As4, int* tile_s, int* ctr,
    const unsigned short* Xin, const int* counts, const int* slots,
    const unsigned short* WT, const float* bias,
    unsigned short* Hout, float* outf)
{
    while (true) {
        if (threadIdx.x == 0) *tile_s = atomicAdd(ctr, 1);
        __syncthreads();
        int tile = *tile_s;
        if (tile >= LAYER_TILES) break;
        layer_tile<RELU, OUT_BF16>(tile * 32, As4, Xin, counts, slots, WT,
                                   bias, Hout, outf);
        __syncthreads();   // As4 + tile_s safe to reuse
    }
}

// ---------- single cooperative kernel: zero+CVT+WT | BUILD | layer1 | layer2 ----------
__global__ __launch_bounds__(256, 4) void fused_kernel(
    const float* __restrict__ x, const int* __restrict__ ei,
    const float* __restrict__ Wl1, const float* __restrict__ Wr1,
    const float* __restrict__ b1,
    const float* __restrict__ Wl2, const float* __restrict__ Wr2,
    const float* __restrict__ b2,
    unsigned short* __restrict__ A0, unsigned short* __restrict__ A1,
    unsigned short* __restrict__ WT,
    int* __restrict__ counts, int* __restrict__ slots,
    int* __restrict__ tctr, float* __restrict__ out)
{
    __shared__ uint4 As4[32 * 33];            // 16.5 KB
    __shared__ int tile_s;
    cg::grid_group grid = cg::this_grid();
    const int gsz = gridDim.x * 256;
    const int gt = blockIdx.x * 256 + threadIdx.x;

    // ---- phase 0: zero counts/ctrs, WT convert, x->bf16 A0 ----
    for (int i = gt; i < N_NODES; i += gsz) counts[i] = 0;
    if (gt == 0) { tctr[0] = 0; tctr[1] = 0; }
    for (int i = gt; i < 2 * D * K2; i += gsz) {
        int layer = i >> 15, rem = i & 32767;
        int n = rem >> 8, k = rem & 255;
        const float* Wl = layer ? Wl2 : Wl1;
        const float* Wr = layer ? Wr2 : Wr1;
        float v = (k < D) ? Wl[k * D + n] : Wr[(k - D) * D + n];
        WT[((size_t)layer << 15) + n * K2 + k] = f32_to_bf16_rne(v);
    }
    for (int i = gt; i < N_NODES * 16; i += gsz) {
        int node = i >> 4, g = i & 15;
        const float4* xp = (const float4*)(x + (size_t)node * D + g * 8);
        float4 v0 = xp[0], v1 = xp[1];
        uint4 o;
        o.x = pk2(v0.x, v0.y); o.y = pk2(v0.z, v0.w);
        o.z = pk2(v1.x, v1.y); o.w = pk2(v1.z, v1.w);
        ((uint4*)A0)[(size_t)node * 16 + g] = o;
    }
    __threadfence();
    grid.sync();

    // ---- phase 1: slot-table BUILD (whole machine, 4 edges/thread) ----
    for (int e4 = gt * 4; e4 < N_EDGES; e4 += gsz * 4) {  // N_EDGES % 4 == 0
        int4 s4 = *(const int4*)(ei + e4);
        int4 d4 = *(const int4*)(ei + N_EDGES + e4);
        int p0 = atomicAdd(&counts[d4.x], 1);
        int p1 = atomicAdd(&counts[d4.y], 1);
        int p2 = atomicAdd(&counts[d4.z], 1);
        int p3 = atomicAdd(&counts[d4.w], 1);
        if (p0 < MAXDEG) slots[(size_t)d4.x * MAXDEG + p0] = s4.x;
        if (p1 < MAXDEG) slots[(size_t)d4.y * MAXDEG + p1] = s4.y;
        if (p2 < MAXDEG) slots[(size_t)d4.z * MAXDEG + p2] = s4.z;
        if (p3 < MAXDEG) slots[(size_t)d4.w * MAXDEG + p3] = s4.w;
    }
    __threadfence();
    grid.sync();

    // ---- phase 2: layer 1 (relu, bf16 out to A1) ----
    layer_phase<true, true>(As4, &tile_s, &tctr[0], A0, counts, slots,
                            WT, b1, A1, nullptr);
    __threadfence();
    grid.sync();

    // ---- phase 3: layer 2 (f32 out) ----
    layer_phase<false, false>(As4, &tile_s, &tctr[1], A1, counts, slots,
                              WT + (size_t)D * K2, b2, nullptr, out);
}

extern "C" void kernel_launch(void* const* d_in, const int* in_sizes, int n_in,
                              void* d_out, int out_size, void* d_ws, size_t ws_size,
                              hipStream_t stream) {
    const float* x   = (const float*)d_in[0];
    const int*   ei  = (const int*)d_in[1];
    const float* Wl1 = (const float*)d_in[2];
    const float* Wr1 = (const float*)d_in[3];
    const float* b1  = (const float*)d_in[4];
    const float* Wl2 = (const float*)d_in[5];
    const float* Wr2 = (const float*)d_in[6];
    const float* b2  = (const float*)d_in[7];
    float* out = (float*)d_out;

    // ws: A0 [N][128] bf16 | A1 [N][128] bf16 | WT [2][128][256] bf16 |
    //     counts [N] | slots [N][MAXDEG] | tctr [2]  (~38.7 MB)
    unsigned short* A0 = (unsigned short*)d_ws;
    unsigned short* A1 = A0 + (size_t)N_NODES * D;
    unsigned short* WT = A1 + (size_t)N_NODES * D;
    int* counts = (int*)(WT + 2 * D * K2);
    int* slots  = counts + N_NODES;
    int* tctr   = slots + (size_t)N_NODES * MAXDEG;

    // co-resident grid: query occupancy, cap at MAX_GRID (all loops grid-stride
    // or dynamically stolen, so any grid size is correct)
    int occ = 4;
    (void)hipOccupancyMaxActiveBlocksPerMultiprocessor(
        &occ, reinterpret_cast<const void*>(fused_kernel), 256, 0);
    if (occ < 1) occ = 1;
    int grid = occ * 256;                      // 256 CUs on MI355X
    if (grid > MAX_GRID) grid = MAX_GRID;

    void* args[] = { (void*)&x, (void*)&ei, (void*)&Wl1, (void*)&Wr1, (void*)&b1,
                     (void*)&Wl2, (void*)&Wr2, (void*)&b2, (void*)&A0, (void*)&A1,
                     (void*)&WT, (void*)&counts, (void*)&slots, (void*)&tctr,
                     (void*)&out };
    hipLaunchCooperativeKernel(reinterpret_cast<const void*>(fused_kernel),
                               dim3(grid), dim3(256), args, 0, stream);
}

// Round 8
// 204.611 us; speedup vs baseline: 2.8181x; 2.8181x over previous
//
#include <hip/hip_runtime.h>
#include <hip/hip_bf16.h>

#define N_NODES 50000
#define N_EDGES 600000
#define D 128
#define K2 256     // 2*D
#define MAXDEG 64  // Poisson(12): max over 50K nodes ~ 33; 64 is safe capacity

// prep: BUILD fused into the first 150016 CVT threads (4 edges each) so the
// streaming loads/stores in the same wave hide the atomic->scatter latency.
// (r5 measured this prep < 46 us — best variant.)
#define CVT_BLOCKS   (N_NODES * 16 / 256)                 // 3125
#define PREPW_BLOCKS (2 * D * K2 / 256)                   // 256
#define PREP_GRID (CVT_BLOCKS + PREPW_BLOCKS)

typedef __bf16 bf16x8 __attribute__((ext_vector_type(8)));
typedef float  f32x16 __attribute__((ext_vector_type(16)));

__device__ __forceinline__ unsigned short f32_to_bf16_rne(float f) {
    unsigned int u = __builtin_bit_cast(unsigned int, f);
    unsigned int r = (u + 0x7fffu + ((u >> 16) & 1u)) >> 16;
    return (unsigned short)r;
}
__device__ __forceinline__ unsigned pk2(float lo, float hi) {
    return (unsigned)f32_to_bf16_rne(lo) | ((unsigned)f32_to_bf16_rne(hi) << 16);
}
__device__ __forceinline__ float bfl(unsigned int u) { return __builtin_bit_cast(float, u << 16); }
__device__ __forceinline__ float bfh(unsigned int u) { return __builtin_bit_cast(float, u & 0xffff0000u); }

// ---------- fused prep: x->bf16 A0 (+BUILD fused in) | W->WT bf16 ----------
__global__ __launch_bounds__(256) void prep_kernel(
    const float* __restrict__ x, const int* __restrict__ ei,
    const float* __restrict__ Wl1, const float* __restrict__ Wr1,
    const float* __restrict__ Wl2, const float* __restrict__ Wr2,
    unsigned short* __restrict__ A0, unsigned short* __restrict__ WT,
    int* __restrict__ counts, int* __restrict__ slots)
{
    const int b = blockIdx.x;
    if (b < CVT_BLOCKS) {
        int idx = b * 256 + threadIdx.x;       // 0..799999
        // ---- BUILD slice: threads with idx*4 < N_EDGES handle 4 edges ----
        int e4 = idx * 4;
        int4 s4 = {0,0,0,0}, d4 = {0,0,0,0};
        const bool doE = e4 < N_EDGES;         // N_EDGES % 4 == 0
        if (doE) {
            s4 = *(const int4*)(ei + e4);
            d4 = *(const int4*)(ei + N_EDGES + e4);
        }
        // ---- CVT slice: 8 features ----
        int node = idx >> 4, g = idx & 15;
        const float4* xp = (const float4*)(x + (size_t)node * D + g * 8);
        float4 v0 = xp[0], v1 = xp[1];
        if (doE) {
            int p0 = atomicAdd(&counts[d4.x], 1);
            int p1 = atomicAdd(&counts[d4.y], 1);
            int p2 = atomicAdd(&counts[d4.z], 1);
            int p3 = atomicAdd(&counts[d4.w], 1);
            if (p0 < MAXDEG) slots[(size_t)d4.x * MAXDEG + p0] = s4.x;
            if (p1 < MAXDEG) slots[(size_t)d4.y * MAXDEG + p1] = s4.y;
            if (p2 < MAXDEG) slots[(size_t)d4.z * MAXDEG + p2] = s4.z;
            if (p3 < MAXDEG) slots[(size_t)d4.w * MAXDEG + p3] = s4.w;
        }
        uint4 o;
        o.x = pk2(v0.x, v0.y); o.y = pk2(v0.z, v0.w);
        o.z = pk2(v1.x, v1.y); o.w = pk2(v1.z, v1.w);
        ((uint4*)A0)[(size_t)node * 16 + g] = o;
    } else {
        // WT[layer][n][k]: k<128 -> Wl[k][n], k>=128 -> Wr[k-128][n]
        int idx = (b - CVT_BLOCKS) * 256 + threadIdx.x;   // 65536 exactly
        int layer = idx >> 15, rem = idx & 32767;
        int n = rem >> 8, k = rem & 255;
        const float* Wl = layer ? Wl2 : Wl1;
        const float* Wr = layer ? Wr2 : Wr1;
        float v = (k < D) ? Wl[k * D + n] : Wr[(k - D) * D + n];
        WT[((size_t)layer << 15) + n * K2 + k] = f32_to_bf16_rne(v);
    }
}

// ---------- fused layer: group-per-node gather -> LDS A-tile -> MFMA ----------
// Block = 256 thr (4 waves), 32 nodes; wave handles 8 nodes as 2 slots x 4 groups.
// Lane = (g,u): g=lane>>4 node within slot, u=lane&15 uint4 of the 256B row.
// Group accumulates its node fully in-lane => no cross-lane reduce.
// Gather in 8-edge chunks (3-phase: bpermute idx / batch loads / masked accum);
// 8 x uint4 = 32 data VGPRs per batch, sized to fit the 64-VGPR cap of
// __launch_bounds__(256,8) WITHOUT spill. The (256,8) bound is the round-8
// lever: LDS 16.5KB allows 8 blocks/CU, doubling resident waves 16->32/CU and
// thus total gather loads in flight (r5: occ 27-38% @ (256,4) was the limit).
// LDS As4[frag*33+m]; GEMM: wave wv cols [wv*32,wv*32+32), K=256, 16x MFMA
// 32x32x16 bf16. C/D: col=lane&31, row=(reg&3)+8*(reg>>2)+4*(lane>>5).
template <bool RELU, bool OUT_BF16>
__global__ __launch_bounds__(256, 8) void layer_kernel(
    const unsigned short* __restrict__ Xin,   // [N][128] bf16
    const int* __restrict__ counts, const int* __restrict__ slots,
    const unsigned short* __restrict__ WT,    // [128][256] bf16 (one layer)
    const float* __restrict__ bias,
    unsigned short* __restrict__ Hout,        // layer1: h bf16 [N][128]
    float* __restrict__ outf)                 // layer2: f32 [N][128]
{
    __shared__ uint4 As4[32 * 33];            // 16.5 KB
    const int tid = threadIdx.x;
    const int lane = tid & 63;
    const int wv = tid >> 6;                  // wave 0..3
    const int base = blockIdx.x * 32;
    const int g = lane >> 4;                  // node-group 0..3
    const int u = lane & 15;                  // uint4 within row
    const uint4* X4 = (const uint4*)Xin;      // row stride = 16 uint4
    const int nodeb = base + wv * 8;

    const int n0 = nodeb + g;                 // slot-0 node of this group
    const int n1 = nodeb + 4 + g;             // slot-1 node
    const bool ok0 = n0 < N_NODES, ok1 = n1 < N_NODES;

    // ---- issue independent loads up front ----
    int cnt0 = 0, cnt1 = 0;
    if (ok0) cnt0 = counts[n0];
    if (ok1) cnt1 = counts[n1];

    int sreg[2][4];                           // slot rows distributed over lanes
    #pragma unroll
    for (int r = 0; r < 4; ++r) {
        sreg[0][r] = ok0 ? slots[(size_t)n0 * MAXDEG + r * 16 + u] : 0;
        sreg[1][r] = ok1 ? slots[(size_t)n1 * MAXDEG + r * 16 + u] : 0;
    }

    uint4 xv0 = {0u,0u,0u,0u}, xv1 = {0u,0u,0u,0u};   // self rows (written at end)
    if (ok0) xv0 = X4[(size_t)n0 * 16 + u];
    if (ok1) xv1 = X4[(size_t)n1 * 16 + u];

    cnt0 = cnt0 > MAXDEG ? MAXDEG : cnt0;
    cnt1 = cnt1 > MAXDEG ? MAXDEG : cnt1;

    // ---- gather: 2 slots ----
    #pragma unroll
    for (int s = 0; s < 2; ++s) {
        const int m = wv * 8 + s * 4 + g;
        const int cnt = s ? cnt1 : cnt0;
        float a0 = 0.f, a1 = 0.f, a2 = 0.f, a3 = 0.f;
        float a4 = 0.f, a5 = 0.f, a6 = 0.f, a7 = 0.f;

        #pragma unroll
        for (int c = 0; c < 8; ++c) {         // 8-edge chunks
            if (c == 0 || __any(cnt > c * 8)) {
                // A: indices (clamped -> safe unconditional loads)
                int idxv[8];
                #pragma unroll
                for (int e = 0; e < 8; ++e) {
                    int t = __shfl(sreg[s][c >> 1], g * 16 + (c & 1) * 8 + e, 64);
                    idxv[e] = (c * 8 + e < cnt) ? t : 0;
                }
                // B: 8 independent loads in flight (32 data VGPRs)
                uint4 vv[8];
                #pragma unroll
                for (int e = 0; e < 8; ++e)
                    vv[e] = X4[(size_t)idxv[e] * 16 + u];
                // C: masked accumulate
                #pragma unroll
                for (int e = 0; e < 8; ++e) {
                    if (c * 8 + e < cnt) {
                        a0 += bfl(vv[e].x); a1 += bfh(vv[e].x);
                        a2 += bfl(vv[e].y); a3 += bfh(vv[e].y);
                        a4 += bfl(vv[e].z); a5 += bfh(vv[e].z);
                        a6 += bfl(vv[e].w); a7 += bfh(vv[e].w);
                    }
                }
            }
        }

        const float inv = 1.0f / fmaxf((float)cnt, 1.0f);
        uint4 o;
        o.x = pk2(a0 * inv, a1 * inv); o.y = pk2(a2 * inv, a3 * inv);
        o.z = pk2(a4 * inv, a5 * inv); o.w = pk2(a6 * inv, a7 * inv);
        As4[u * 33 + m] = o;                  // all 64 lanes: 4 nodes at once
    }

    // self half: frag 16+u
    As4[(16 + u) * 33 + (wv * 8 + g)]     = xv0;
    As4[(16 + u) * 33 + (wv * 8 + 4 + g)] = xv1;

    __syncthreads();

    // ---- GEMM phase ----
    const int m = lane & 31;
    const int kg = lane >> 5;
    const int col = wv * 32 + m;
    const uint4* bp = (const uint4*)(WT + (size_t)col * K2 + kg * 8);
    const bf16x8* afrag = (const bf16x8*)As4;

    f32x16 acc = {};
    #pragma unroll
    for (int s = 0; s < 16; ++s) {
        bf16x8 a = afrag[(s * 2 + kg) * 33 + m];
        bf16x8 b = __builtin_bit_cast(bf16x8, bp[s * 2]);
        acc = __builtin_amdgcn_mfma_f32_32x32x16_bf16(a, b, acc, 0, 0, 0);
    }

    const float bc = bias[col];
    const int halfadd = kg * 4;
    #pragma unroll
    for (int r = 0; r < 16; ++r) {
        int rw = base + (r & 3) + 8 * (r >> 2) + halfadd;
        if (rw < N_NODES) {
            float v = acc[r] + bc;
            if (RELU) v = fmaxf(v, 0.0f);
            if (OUT_BF16) Hout[(size_t)rw * D + col] = f32_to_bf16_rne(v);
            else outf[(size_t)rw * D + col] = v;
        }
    }
}

extern "C" void kernel_launch(void* const* d_in, const int* in_sizes, int n_in,
                              void* d_out, int out_size, void* d_ws, size_t ws_size,
                              hipStream_t stream) {
    const float* x   = (const float*)d_in[0];
    const int*   ei  = (const int*)d_in[1];
    const float* Wl1 = (const float*)d_in[2];
    const float* Wr1 = (const float*)d_in[3];
    const float* b1  = (const float*)d_in[4];
    const float* Wl2 = (const float*)d_in[5];
    const float* Wr2 = (const float*)d_in[6];
    const float* b2  = (const float*)d_in[7];
    float* out = (float*)d_out;

    // ws: A0 [N][128] bf16 | A1 [N][128] bf16 | WT [2][128][256] bf16 |
    //     counts [N] | slots [N][MAXDEG]  (~38.7 MB)
    unsigned short* A0 = (unsigned short*)d_ws;
    unsigned short* A1 = A0 + (size_t)N_NODES * D;
    unsigned short* WT = A1 + (size_t)N_NODES * D;
    int* counts = (int*)(WT + 2 * D * K2);
    int* slots  = counts + N_NODES;

    const int layerBlocks = (N_NODES + 31) / 32;  // 1563

    hipMemsetAsync(counts, 0, N_NODES * sizeof(int), stream);
    prep_kernel<<<PREP_GRID, 256, 0, stream>>>(x, ei, Wl1, Wr1, Wl2, Wr2, A0, WT, counts, slots);

    layer_kernel<true, true><<<layerBlocks, 256, 0, stream>>>(
        A0, counts, slots, WT, b1, A1, nullptr);
    layer_kernel<false, false><<<layerBlocks, 256, 0, stream>>>(
        A1, counts, slots, WT + (size_t)D * K2, b2, nullptr, out);
}

// Round 9
// 201.537 us; speedup vs baseline: 2.8610x; 1.0153x over previous
//
#include <hip/hip_runtime.h>
#include <hip/hip_bf16.h>

#define N_NODES 50000
#define N_EDGES 600000
#define D 128
#define K2 256     // 2*D
#define MAXDEG 64  // Poisson(12): max over 50K nodes ~ 33; 64 is safe capacity

// prep (r3-measured-best shape): CVT | BUILD (4 edges/thr) | WT
#define CVT_BLOCKS   (N_NODES * 16 / 256)                 // 3125
#define BUILD_BLOCKS ((N_EDGES / 4 + 255) / 256)          // 586
#define PREPW_BLOCKS (2 * D * K2 / 256)                   // 256
#define PREP_GRID (CVT_BLOCKS + BUILD_BLOCKS + PREPW_BLOCKS)

typedef __bf16 bf16x8 __attribute__((ext_vector_type(8)));
typedef float  f32x16 __attribute__((ext_vector_type(16)));

__device__ __forceinline__ unsigned short f32_to_bf16_rne(float f) {
    unsigned int u = __builtin_bit_cast(unsigned int, f);
    unsigned int r = (u + 0x7fffu + ((u >> 16) & 1u)) >> 16;
    return (unsigned short)r;
}
__device__ __forceinline__ unsigned pk2(float lo, float hi) {
    return (unsigned)f32_to_bf16_rne(lo) | ((unsigned)f32_to_bf16_rne(hi) << 16);
}
__device__ __forceinline__ float bfl(unsigned int u) { return __builtin_bit_cast(float, u << 16); }
__device__ __forceinline__ float bfh(unsigned int u) { return __builtin_bit_cast(float, u & 0xffff0000u); }

// ---------- fused prep: x->bf16 A0 | slot-table CSR build (4 edges/thr) | W->WT bf16 ----------
__global__ __launch_bounds__(256) void prep_kernel(
    const float* __restrict__ x, const int* __restrict__ ei,
    const float* __restrict__ Wl1, const float* __restrict__ Wr1,
    const float* __restrict__ Wl2, const float* __restrict__ Wr2,
    unsigned short* __restrict__ A0, unsigned short* __restrict__ WT,
    int* __restrict__ counts, int* __restrict__ slots)
{
    const int b = blockIdx.x;
    if (b < CVT_BLOCKS) {
        // x [N][128] f32 -> A0 [N][128] bf16; thread = 8 features
        int idx = b * 256 + threadIdx.x;       // 800000 exactly
        int node = idx >> 4, g = idx & 15;
        const float4* xp = (const float4*)(x + (size_t)node * D + g * 8);
        float4 v0 = xp[0], v1 = xp[1];
        uint4 o;
        o.x = pk2(v0.x, v0.y); o.y = pk2(v0.z, v0.w);
        o.z = pk2(v1.x, v1.y); o.w = pk2(v1.z, v1.w);
        ((uint4*)A0)[(size_t)node * 16 + g] = o;
    } else if (b < CVT_BLOCKS + BUILD_BLOCKS) {
        // one-pass CSR into fixed-capacity slot table, 4 edges/thread for MLP
        int e4 = ((b - CVT_BLOCKS) * 256 + threadIdx.x) * 4;
        if (e4 < N_EDGES) {   // N_EDGES % 4 == 0, whole int4 valid
            int4 s4 = *(const int4*)(ei + e4);
            int4 d4 = *(const int4*)(ei + N_EDGES + e4);
            int p0 = atomicAdd(&counts[d4.x], 1);
            int p1 = atomicAdd(&counts[d4.y], 1);
            int p2 = atomicAdd(&counts[d4.z], 1);
            int p3 = atomicAdd(&counts[d4.w], 1);
            if (p0 < MAXDEG) slots[(size_t)d4.x * MAXDEG + p0] = s4.x;
            if (p1 < MAXDEG) slots[(size_t)d4.y * MAXDEG + p1] = s4.y;
            if (p2 < MAXDEG) slots[(size_t)d4.z * MAXDEG + p2] = s4.z;
            if (p3 < MAXDEG) slots[(size_t)d4.w * MAXDEG + p3] = s4.w;
        }
    } else {
        // WT[layer][n][k]: k<128 -> Wl[k][n], k>=128 -> Wr[k-128][n]
        int idx = (b - CVT_BLOCKS - BUILD_BLOCKS) * 256 + threadIdx.x;  // 65536
        int layer = idx >> 15, rem = idx & 32767;
        int n = rem >> 8, k = rem & 255;
        const float* Wl = layer ? Wl2 : Wl1;
        const float* Wr = layer ? Wr2 : Wr1;
        float v = (k < D) ? Wl[k * D + n] : Wr[(k - D) * D + n];
        WT[((size_t)layer << 15) + n * K2 + k] = f32_to_bf16_rne(v);
    }
}

// ---------- fused layer: group-per-node gather (lazy slot rows) -> LDS -> MFMA ----------
// Block = 256 thr (4 waves), 32 nodes; wave handles 8 nodes as 2 slots x 4 groups.
// Lane = (g,u): g=lane>>4 node within slot, u=lane&15 uint4 of the 256B row.
// Group accumulates its node fully in-lane => no cross-lane reduce.
// Slot rows are loaded LAZILY: row 0 (edges 0..15) unconditional; rows 1..3
// exec-masked by the group's own cnt (each row slice = 16 x 4B = exactly one
// 64B L2 line). This cuts ~18MB/layer of slot traffic vs the unconditional
// 256B/node preload — the layers are at a random-traffic throughput wall
// (r8: occupancy x2 => no time change), so bytes are the only lever left.
// Gather in 8-edge chunks (3-phase: bpermute idx / batch loads / masked accum).
// LDS As4[frag*33+m]; GEMM: wave wv cols [wv*32,wv*32+32), K=256, 16x MFMA
// 32x32x16 bf16. C/D: col=lane&31, row=(reg&3)+8*(reg>>2)+4*(lane>>5).
template <bool RELU, bool OUT_BF16>
__global__ __launch_bounds__(256, 8) void layer_kernel(
    const unsigned short* __restrict__ Xin,   // [N][128] bf16
    const int* __restrict__ counts, const int* __restrict__ slots,
    const unsigned short* __restrict__ WT,    // [128][256] bf16 (one layer)
    const float* __restrict__ bias,
    unsigned short* __restrict__ Hout,        // layer1: h bf16 [N][128]
    float* __restrict__ outf)                 // layer2: f32 [N][128]
{
    __shared__ uint4 As4[32 * 33];            // 16.5 KB
    const int tid = threadIdx.x;
    const int lane = tid & 63;
    const int wv = tid >> 6;                  // wave 0..3
    const int base = blockIdx.x * 32;
    const int g = lane >> 4;                  // node-group 0..3
    const int u = lane & 15;                  // uint4 within row
    const uint4* X4 = (const uint4*)Xin;      // row stride = 16 uint4
    const int nodeb = base + wv * 8;

    const int n0 = nodeb + g;                 // slot-0 node of this group
    const int n1 = nodeb + 4 + g;             // slot-1 node
    const bool ok0 = n0 < N_NODES, ok1 = n1 < N_NODES;

    // ---- independent up-front loads: counts, slot row 0, self rows ----
    int cnt0 = 0, cnt1 = 0;
    if (ok0) cnt0 = counts[n0];
    if (ok1) cnt1 = counts[n1];

    int srow0[2];                             // row 0 of each slot's node
    srow0[0] = ok0 ? slots[(size_t)n0 * MAXDEG + u] : 0;
    srow0[1] = ok1 ? slots[(size_t)n1 * MAXDEG + u] : 0;

    uint4 xv0 = {0u,0u,0u,0u}, xv1 = {0u,0u,0u,0u};   // self rows (written at end)
    if (ok0) xv0 = X4[(size_t)n0 * 16 + u];
    if (ok1) xv1 = X4[(size_t)n1 * 16 + u];

    cnt0 = cnt0 > MAXDEG ? MAXDEG : cnt0;
    cnt1 = cnt1 > MAXDEG ? MAXDEG : cnt1;

    // ---- gather: 2 slots ----
    #pragma unroll
    for (int s = 0; s < 2; ++s) {
        const int m = wv * 8 + s * 4 + g;
        const int cnt = s ? cnt1 : cnt0;
        const int nn  = s ? n1 : n0;
        int srow = srow0[s];                  // current row (r = c>>1)
        float a0 = 0.f, a1 = 0.f, a2 = 0.f, a3 = 0.f;
        float a4 = 0.f, a5 = 0.f, a6 = 0.f, a7 = 0.f;

        #pragma unroll
        for (int c = 0; c < 8; ++c) {         // 8-edge chunks
            if (c == 0 || __any(cnt > c * 8)) {
                // lazy row fetch at even chunks >0 (one 64B line per group,
                // exec-masked by the group's own cnt)
                if ((c & 1) == 0 && c > 0) {
                    srow = (cnt > c * 8)
                         ? slots[(size_t)nn * MAXDEG + (c >> 1) * 16 + u] : 0;
                }
                // A: indices (clamped -> safe unconditional loads; slots
                //    beyond cnt are uninitialized, masked at accumulate)
                int idxv[8];
                #pragma unroll
                for (int e = 0; e < 8; ++e) {
                    int t = __shfl(srow, g * 16 + (c & 1) * 8 + e, 64);
                    idxv[e] = (c * 8 + e < cnt) ? t : 0;
                }
                // B: 8 independent loads in flight (32 data VGPRs)
                uint4 vv[8];
                #pragma unroll
                for (int e = 0; e < 8; ++e)
                    vv[e] = X4[(size_t)idxv[e] * 16 + u];
                // C: masked accumulate
                #pragma unroll
                for (int e = 0; e < 8; ++e) {
                    if (c * 8 + e < cnt) {
                        a0 += bfl(vv[e].x); a1 += bfh(vv[e].x);
                        a2 += bfl(vv[e].y); a3 += bfh(vv[e].y);
                        a4 += bfl(vv[e].z); a5 += bfh(vv[e].z);
                        a6 += bfl(vv[e].w); a7 += bfh(vv[e].w);
                    }
                }
            }
        }

        const float inv = 1.0f / fmaxf((float)cnt, 1.0f);
        uint4 o;
        o.x = pk2(a0 * inv, a1 * inv); o.y = pk2(a2 * inv, a3 * inv);
        o.z = pk2(a4 * inv, a5 * inv); o.w = pk2(a6 * inv, a7 * inv);
        As4[u * 33 + m] = o;                  // all 64 lanes: 4 nodes at once
    }

    // self half: frag 16+u
    As4[(16 + u) * 33 + (wv * 8 + g)]     = xv0;
    As4[(16 + u) * 33 + (wv * 8 + 4 + g)] = xv1;

    __syncthreads();

    // ---- GEMM phase ----
    const int m = lane & 31;
    const int kg = lane >> 5;
    const int col = wv * 32 + m;
    const uint4* bp = (const uint4*)(WT + (size_t)col * K2 + kg * 8);
    const bf16x8* afrag = (const bf16x8*)As4;

    f32x16 acc = {};
    #pragma unroll
    for (int s = 0; s < 16; ++s) {
        bf16x8 a = afrag[(s * 2 + kg) * 33 + m];
        bf16x8 b = __builtin_bit_cast(bf16x8, bp[s * 2]);
        acc = __builtin_amdgcn_mfma_f32_32x32x16_bf16(a, b, acc, 0, 0, 0);
    }

    const float bc = bias[col];
    const int halfadd = kg * 4;
    #pragma unroll
    for (int r = 0; r < 16; ++r) {
        int rw = base + (r & 3) + 8 * (r >> 2) + halfadd;
        if (rw < N_NODES) {
            float v = acc[r] + bc;
            if (RELU) v = fmaxf(v, 0.0f);
            if (OUT_BF16) Hout[(size_t)rw * D + col] = f32_to_bf16_rne(v);
            else outf[(size_t)rw * D + col] = v;
        }
    }
}

extern "C" void kernel_launch(void* const* d_in, const int* in_sizes, int n_in,
                              void* d_out, int out_size, void* d_ws, size_t ws_size,
                              hipStream_t stream) {
    const float* x   = (const float*)d_in[0];
    const int*   ei  = (const int*)d_in[1];
    const float* Wl1 = (const float*)d_in[2];
    const float* Wr1 = (const float*)d_in[3];
    const float* b1  = (const float*)d_in[4];
    const float* Wl2 = (const float*)d_in[5];
    const float* Wr2 = (const float*)d_in[6];
    const float* b2  = (const float*)d_in[7];
    float* out = (float*)d_out;

    // ws: A0 [N][128] bf16 | A1 [N][128] bf16 | WT [2][128][256] bf16 |
    //     counts [N] | slots [N][MAXDEG]  (~38.7 MB)
    unsigned short* A0 = (unsigned short*)d_ws;
    unsigned short* A1 = A0 + (size_t)N_NODES * D;
    unsigned short* WT = A1 + (size_t)N_NODES * D;
    int* counts = (int*)(WT + 2 * D * K2);
    int* slots  = counts + N_NODES;

    const int layerBlocks = (N_NODES + 31) / 32;  // 1563

    hipMemsetAsync(counts, 0, N_NODES * sizeof(int), stream);
    prep_kernel<<<PREP_GRID, 256, 0, stream>>>(x, ei, Wl1, Wr1, Wl2, Wr2, A0, WT, counts, slots);

    layer_kernel<true, true><<<layerBlocks, 256, 0, stream>>>(
        A0, counts, slots, WT, b1, A1, nullptr);
    layer_kernel<false, false><<<layerBlocks, 256, 0, stream>>>(
        A1, counts, slots, WT + (size_t)D * K2, b2, nullptr, out);
}